// Round 1
// baseline (209.581 us; speedup 1.0000x reference)
//
#include <hip/hip_runtime.h>

#define FF_DEPTH 4096   // n = 4096 = 64 * 64

// In-register 64-point unnormalized Walsh-Hadamard transform.
// Fully static indexing so v[] stays in VGPRs (no scratch).
__device__ __forceinline__ void h64(float v[64]) {
#pragma unroll
    for (int b = 1; b < 64; b <<= 1) {
#pragma unroll
        for (int r = 0; r < 64; ++r) {
            if ((r & b) == 0) {
                const float u = v[r];
                const float w = v[r | b];
                v[r]     = u + w;
                v[r | b] = u - w;
            }
        }
    }
}

// One wave (64 threads) per row. H_4096 = H_64 (high 6 bits) (x) H_64 (low 6 bits);
// stage order across distinct bits commutes, so each H_64 is done fully in
// registers; LDS is used only for 2 transposes + 1 permutation gather per row.
// LDS padded by 1 dword per 64 (addr = i + (i>>6)) -> every access pattern is
// exactly 2 lanes/bank (conflict-free on 32 banks).
__global__ __launch_bounds__(64) void fastfood_fwht_kernel(
    const float* __restrict__ x,
    const float* __restrict__ diag_s,
    const float* __restrict__ diag_g,
    const float* __restrict__ diag_b,
    const int*   __restrict__ perm,
    float* __restrict__ out)
{
    __shared__ float lds[FF_DEPTH + (FF_DEPTH >> 6)];
    const int t = threadIdx.x;                 // lane 0..63
    const size_t row = blockIdx.x;
    const float* __restrict__ xr   = x   + row * FF_DEPTH;
    float* __restrict__       outr = out + row * FF_DEPTH;

    float v[64];

    // ---- load in layout2 (v[r] holds element i = r*64 + t): coalesced ----
#pragma unroll
    for (int r = 0; r < 64; ++r) {
        const int i = r * 64 + t;
        v[r] = xr[i] * diag_b[i];
    }

    // FWHT #1, high-bit stages (element strides 64..2048 == register strides 1..32)
    h64(v);

    // transpose layout2 -> layout1 via padded LDS
#pragma unroll
    for (int r = 0; r < 64; ++r) {
        const int i = r * 64 + t;
        lds[i + (i >> 6)] = v[r];
    }
    __syncthreads();
#pragma unroll
    for (int r = 0; r < 64; ++r) {
        const int i = t * 64 + r;
        v[r] = lds[i + (i >> 6)];
    }

    // FWHT #1, low-bit stages (element strides 1..32)
    h64(v);

    // publish FWHT1 result (unnormalized) in natural order
    __syncthreads();                            // all reads done before overwrite
#pragma unroll
    for (int r = 0; r < 64; ++r) {
        const int i = t * 64 + r;
        lds[i + (i >> 6)] = v[r];
    }
    __syncthreads();

    // permutation gather + diag_g (fold FWHT1's 1/64), into layout2
    // (perm/diag_g reads are coalesced; LDS gather is random -> acceptable)
#pragma unroll
    for (int r = 0; r < 64; ++r) {
        const int j = r * 64 + t;
        const int p = perm[j];
        v[r] = lds[p + (p >> 6)] * (diag_g[j] * 0.015625f);
    }

    // FWHT #2, high-bit stages
    h64(v);

    // transpose layout2 -> layout1
    __syncthreads();                            // gather reads done before overwrite
#pragma unroll
    for (int r = 0; r < 64; ++r) {
        const int i = r * 64 + t;
        lds[i + (i >> 6)] = v[r];
    }
    __syncthreads();
#pragma unroll
    for (int r = 0; r < 64; ++r) {
        const int i = t * 64 + r;
        v[r] = lds[i + (i >> 6)];
    }

    // FWHT #2, low-bit stages
    h64(v);

    // store with diag_s (fold FWHT2's 1/64); per-thread contiguous dwordx4,
    // full 64B lines assembled in L2 across the 4-dword groups.
#pragma unroll
    for (int r = 0; r < 64; r += 4) {
        const int i = t * 64 + r;
        const float4 s4 = *reinterpret_cast<const float4*>(&diag_s[i]);
        float4 o;
        o.x = v[r + 0] * s4.x * 0.015625f;
        o.y = v[r + 1] * s4.y * 0.015625f;
        o.z = v[r + 2] * s4.z * 0.015625f;
        o.w = v[r + 3] * s4.w * 0.015625f;
        *reinterpret_cast<float4*>(&outr[i]) = o;
    }
}

extern "C" void kernel_launch(void* const* d_in, const int* in_sizes, int n_in,
                              void* d_out, int out_size, void* d_ws, size_t ws_size,
                              hipStream_t stream) {
    const float* x      = (const float*)d_in[0];
    const float* diag_s = (const float*)d_in[1];
    const float* diag_g = (const float*)d_in[2];
    const float* diag_b = (const float*)d_in[3];
    const int*   perm   = (const int*)d_in[4];
    float* out = (float*)d_out;

    const int batch = in_sizes[0] / FF_DEPTH;   // 16384 rows
    fastfood_fwht_kernel<<<batch, 64, 0, stream>>>(x, diag_s, diag_g, diag_b, perm, out);
}

// Round 3
// 198.429 us; speedup vs baseline: 1.0562x; 1.0562x over previous
//
#include <hip/hip_runtime.h>

#define FF_DEPTH 4096
// fp16 staging buffer, padded 16B per 128 elements (keeps 16B alignment for b128
// ops AND spreads transpose patterns across banks): byte(i) = 2*i + (i>>7)*16
#define LDS_BYTES (2 * FF_DEPTH + (FF_DEPTH / 128) * 16)   // 8192 + 512 = 8704

typedef __fp16 pkhalf2_t __attribute__((ext_vector_type(2)));

__device__ __forceinline__ int ldsOff(int i) { return 2 * i + ((i >> 7) << 4); }

__device__ __forceinline__ unsigned pack2(float a, float b) {
    union { pkhalf2_t h; unsigned u; } cv;
    cv.h = __builtin_amdgcn_cvt_pkrtz(a, b);   // v_cvt_pkrtz_f16_f32
    return cv.u;
}

// In-register 64-point unnormalized Walsh-Hadamard transform (static indexing
// only -> stays in VGPRs).
__device__ __forceinline__ void h64(float v[64]) {
#pragma unroll
    for (int b = 1; b < 64; b <<= 1) {
#pragma unroll
        for (int r = 0; r < 64; ++r) {
            if ((r & b) == 0) {
                const float u = v[r];
                const float w = v[r | b];
                v[r]     = u + w;
                v[r | b] = u - w;
            }
        }
    }
}

// One wave per row. H_4096 = H_64(bits 6..11) (x) H_64(bits 0..5); butterflies
// over distinct bits commute, so each H_64 runs fully in registers and LDS is
// only used (in fp16) for 2 transposes + the permutation gather.
// layout2: v[r] = elem r*64+t (reg bits = elem bits 6..11)
// layout1: v[r] = elem t*64+r (reg bits = elem bits 0..5, per-lane contiguous)
// Normalization 1/4096 split as 4 x (1/8) so staged fp16 values stay ~N(0,1).
__global__ __launch_bounds__(64) void fastfood_fwht_kernel(
    const float* __restrict__ x,
    const float* __restrict__ diag_s,
    const float* __restrict__ diag_g,
    const float* __restrict__ diag_b,
    const int*   __restrict__ perm,
    float* __restrict__ out)
{
    __shared__ __align__(16) unsigned char lds[LDS_BYTES];
    const int t = threadIdx.x;                 // lane 0..63
    const size_t row = blockIdx.x;
    const float* __restrict__ xr   = x   + row * FF_DEPTH;
    float* __restrict__       outr = out + row * FF_DEPTH;

    float v[64];

    // ---- P1: load layout2 (coalesced 256B/instr), * diag_b * 1/8 ----
#pragma unroll
    for (int r = 0; r < 64; ++r) {
        const int i = r * 64 + t;
        v[r] = xr[i] * (diag_b[i] * 0.125f);
    }

    h64(v);   // FWHT1 high bits (6..11)

    // ---- P2w: scatter to natural order, fp16 (b16; 2 lanes/dword = free) ----
#pragma unroll
    for (int r = 0; r < 64; ++r) {
        const int i = r * 64 + t;
        *(__fp16*)(lds + ldsOff(i)) = (__fp16)v[r];
    }
    __syncthreads();

    // ---- P2r: contiguous layout1 read, 8 x ds_read_b128 (bank-balanced) ----
#pragma unroll
    for (int k = 0; k < 8; ++k) {
        const int i = t * 64 + k * 8;
        union { uint4 u; __fp16 h[8]; } q;
        q.u = *(const uint4*)(lds + ldsOff(i));
#pragma unroll
        for (int j = 0; j < 8; ++j) v[k * 8 + j] = (float)q.h[j];
    }
    __syncthreads();

    h64(v);   // FWHT1 low bits (0..5)

    // ---- P4w: stage FWHT1 result (x 1/8) natural order, 8 x ds_write_b128 ----
#pragma unroll
    for (int k = 0; k < 8; ++k) {
        const int i = t * 64 + k * 8;
        uint4 q;
        q.x = pack2(v[k * 8 + 0] * 0.125f, v[k * 8 + 1] * 0.125f);
        q.y = pack2(v[k * 8 + 2] * 0.125f, v[k * 8 + 3] * 0.125f);
        q.z = pack2(v[k * 8 + 4] * 0.125f, v[k * 8 + 5] * 0.125f);
        q.w = pack2(v[k * 8 + 6] * 0.125f, v[k * 8 + 7] * 0.125f);
        *(uint4*)(lds + ldsOff(i)) = q;
    }
    __syncthreads();

    // ---- P5: permutation gather into layout1, * diag_g (int4/float4 loads) ----
#pragma unroll
    for (int k = 0; k < 16; ++k) {
        const int j = t * 64 + k * 4;
        const int4   p4 = *(const int4*)(perm + j);
        const float4 g4 = *(const float4*)(diag_g + j);
        v[k * 4 + 0] = (float)(*(const __fp16*)(lds + ldsOff(p4.x))) * g4.x;
        v[k * 4 + 1] = (float)(*(const __fp16*)(lds + ldsOff(p4.y))) * g4.y;
        v[k * 4 + 2] = (float)(*(const __fp16*)(lds + ldsOff(p4.z))) * g4.z;
        v[k * 4 + 3] = (float)(*(const __fp16*)(lds + ldsOff(p4.w))) * g4.w;
    }
    __syncthreads();

    h64(v);   // FWHT2 low bits (0..5)

    // ---- P6w: stage (x 1/8) natural order, 8 x ds_write_b128 ----
#pragma unroll
    for (int k = 0; k < 8; ++k) {
        const int i = t * 64 + k * 8;
        uint4 q;
        q.x = pack2(v[k * 8 + 0] * 0.125f, v[k * 8 + 1] * 0.125f);
        q.y = pack2(v[k * 8 + 2] * 0.125f, v[k * 8 + 3] * 0.125f);
        q.z = pack2(v[k * 8 + 4] * 0.125f, v[k * 8 + 5] * 0.125f);
        q.w = pack2(v[k * 8 + 6] * 0.125f, v[k * 8 + 7] * 0.125f);
        *(uint4*)(lds + ldsOff(i)) = q;
    }
    __syncthreads();

    // ---- P6r: layout2 scatter read (b16; free) ----
#pragma unroll
    for (int r = 0; r < 64; ++r) {
        const int i = r * 64 + t;
        v[r] = (float)(*(const __fp16*)(lds + ldsOff(i)));
    }

    h64(v);   // FWHT2 high bits (6..11)

    // ---- P7: store layout2 (coalesced 256B/instr), * diag_s * 1/8 ----
#pragma unroll
    for (int r = 0; r < 64; ++r) {
        const int i = r * 64 + t;
        outr[i] = v[r] * (diag_s[i] * 0.125f);
    }
}

extern "C" void kernel_launch(void* const* d_in, const int* in_sizes, int n_in,
                              void* d_out, int out_size, void* d_ws, size_t ws_size,
                              hipStream_t stream) {
    const float* x      = (const float*)d_in[0];
    const float* diag_s = (const float*)d_in[1];
    const float* diag_g = (const float*)d_in[2];
    const float* diag_b = (const float*)d_in[3];
    const int*   perm   = (const int*)d_in[4];
    float* out = (float*)d_out;

    const int batch = in_sizes[0] / FF_DEPTH;   // 16384 rows
    fastfood_fwht_kernel<<<batch, 64, 0, stream>>>(x, diag_s, diag_g, diag_b, perm, out);
}

// Round 4
// 177.633 us; speedup vs baseline: 1.1799x; 1.1171x over previous
//
#include <hip/hip_runtime.h>

#define FF_N 4096

// MFMA fragment types (builtins use __fp16-based vectors per hipcc diagnostics)
typedef __fp16 f16x8 __attribute__((ext_vector_type(8)));
typedef __fp16 pk2   __attribute__((ext_vector_type(2)));
typedef float  f32x4 __attribute__((ext_vector_type(4)));

// LDS layout for a 64x64 f16 matrix: element (d, a) at byte (d*128 + 2*a),
// XOR-swizzled in 16B/32B units so that (i) b64 frag-writes are 4-pass optimal,
// (ii) per-j b16 frag-reads land on disjoint 8-dword bank windows per lane
// group (conflict-free). Bijective; fits exactly in 8192 B.
__device__ __forceinline__ int swzb(int d, int a) {
    return (d * 128 + 2 * a) ^ ((d & 7) << 4) ^ ((d & 24) << 2);
}

#define MFMA16(a, b, acc) __builtin_amdgcn_mfma_f32_16x16x32_f16((a), (b), (acc), 0, 0, 0)

// A = H64 fragment for tile (mi, kb): H64[m][k] = (-1)^popcount(m&k),
// m = mi*16 + (l&15), k = kb*32 + (l>>4)*8 + j.  Decomposes as
// baseSign(l,j) ^ (mi0 & (l>=32)) ^ (mi1 & kb)  -> 2 base frags + sign flip.
#define AF(mi, kb) ((((mi) >> 1) & (kb)) ? (((mi) & 1) ? N1 : N0) : (((mi) & 1) ? F1 : F0))

__global__ __launch_bounds__(64) void fastfood_mfma_kernel(
    const float* __restrict__ x,
    const float* __restrict__ diag_s,
    const float* __restrict__ diag_g,
    const float* __restrict__ diag_b,
    const int*   __restrict__ perm,
    float* __restrict__ out)
{
    __shared__ __align__(16) unsigned char lds[8192];
    const int l = threadIdx.x;
    const int c = l & 15;   // lane within 16-group (MFMA n/m index)
    const int g = l >> 4;   // lane group 0..3    (MFMA k-slice)
    const size_t row = blockIdx.x;
    const float* __restrict__ xr   = x   + row * (size_t)FF_N;
    float* __restrict__       outr = out + row * (size_t)FF_N;

    // ---- H64 A-operand base fragments (exact +-1 in f16, ~50 VALU once) ----
    f16x8 F0, F1, N0, N1;
#pragma unroll
    for (int j = 0; j < 8; ++j) {
        const int kr = g * 8 + j;
        F0[j] = (__fp16)((__builtin_popcount(c & kr) & 1) ? -1.0f : 1.0f);
    }
    F1 = (g >= 2) ? (f16x8)(-F0) : F0;
    N0 = -F0;
    N1 = -F1;

    f32x4 D[4][4];

    // ================= FWHT #1, step a: T1 = H * M =================
    // M[k][n] = x[64k+n] * diag_b * 0.125, loaded straight into B-frag layout
    // (each load = 64 lanes x 4B in 4 x 64B segments -> fully line-coalesced).
#pragma unroll
    for (int mi = 0; mi < 4; ++mi)
#pragma unroll
        for (int ni = 0; ni < 4; ++ni) D[mi][ni] = (f32x4){0.f, 0.f, 0.f, 0.f};

#pragma unroll
    for (int kb = 0; kb < 2; ++kb) {
        f16x8 B[4];
#pragma unroll
        for (int ni = 0; ni < 4; ++ni) {
            union { f16x8 v; pk2 p[4]; } bb;
#pragma unroll
            for (int jp = 0; jp < 4; ++jp) {
                const int i0 = (kb * 32 + g * 8 + jp * 2) * 64 + ni * 16 + c;
                const float a0 = xr[i0]      * (diag_b[i0]      * 0.125f);
                const float a1 = xr[i0 + 64] * (diag_b[i0 + 64] * 0.125f);
                bb.p[jp] = __builtin_amdgcn_cvt_pkrtz(a0, a1);
            }
            B[ni] = bb.v;
        }
#pragma unroll
        for (int ni = 0; ni < 4; ++ni)
#pragma unroll
            for (int mi = 0; mi < 4; ++mi)
                D[mi][ni] = MFMA16(AF(mi, kb), B[ni], D[mi][ni]);
    }

    // j1: stage T1 (f16, ~unit variance) -- layout (d-axis = T1 col, 2B-axis = T1 row)
#pragma unroll
    for (int mi = 0; mi < 4; ++mi)
#pragma unroll
        for (int ni = 0; ni < 4; ++ni) {
            union { unsigned long long u; pk2 p[2]; } w;
            w.p[0] = __builtin_amdgcn_cvt_pkrtz(D[mi][ni][0], D[mi][ni][1]);
            w.p[1] = __builtin_amdgcn_cvt_pkrtz(D[mi][ni][2], D[mi][ni][3]);
            *(unsigned long long*)(lds + swzb(ni * 16 + c, mi * 16 + g * 4)) = w.u;
        }
    __syncthreads();

    // ================= FWHT #1, step b: U = H * T1^T =================
    // B'[k=d][n=a] = T1[a][d] via per-j b16 reads (conflict-free swizzle).
#pragma unroll
    for (int mi = 0; mi < 4; ++mi)
#pragma unroll
        for (int ni = 0; ni < 4; ++ni) D[mi][ni] = (f32x4){0.f, 0.f, 0.f, 0.f};
#pragma unroll
    for (int kb = 0; kb < 2; ++kb) {
        f16x8 B[4];
#pragma unroll
        for (int ni = 0; ni < 4; ++ni)
#pragma unroll
            for (int j = 0; j < 8; ++j)
                B[ni][j] = *(const __fp16*)(lds + swzb(kb * 32 + g * 8 + j, ni * 16 + c));
#pragma unroll
        for (int ni = 0; ni < 4; ++ni)
#pragma unroll
            for (int mi = 0; mi < 4; ++mi)
                D[mi][ni] = MFMA16(AF(mi, kb), B[ni], D[mi][ni]);
    }
    __syncthreads();

    // j2: stage o = 0.125*U; o[64a+e] = U[e][a] at layout (d-axis = a, 2B-axis = e).
    // (o is now the exactly-normalized FWHT1 output: (1/64) folded as 0.125^2.)
#pragma unroll
    for (int mi = 0; mi < 4; ++mi)
#pragma unroll
        for (int ni = 0; ni < 4; ++ni) {
            union { unsigned long long u; pk2 p[2]; } w;
            w.p[0] = __builtin_amdgcn_cvt_pkrtz(D[mi][ni][0] * 0.125f, D[mi][ni][1] * 0.125f);
            w.p[1] = __builtin_amdgcn_cvt_pkrtz(D[mi][ni][2] * 0.125f, D[mi][ni][3] * 0.125f);
            *(unsigned long long*)(lds + swzb(ni * 16 + c, mi * 16 + g * 4)) = w.u;
        }
    __syncthreads();

    // ================= permutation + FWHT #2, step a: T3 = H * W =================
    // W[c2][d2] = o[perm[64*c2+d2]] * diag_g[...]; gather o[p] at (a=p>>6, e=p&63).
#pragma unroll
    for (int mi = 0; mi < 4; ++mi)
#pragma unroll
        for (int ni = 0; ni < 4; ++ni) D[mi][ni] = (f32x4){0.f, 0.f, 0.f, 0.f};
#pragma unroll
    for (int kb = 0; kb < 2; ++kb) {
        f16x8 B[4];
#pragma unroll
        for (int ni = 0; ni < 4; ++ni)
#pragma unroll
            for (int j = 0; j < 8; ++j) {
                const int jj = (kb * 32 + g * 8 + j) * 64 + ni * 16 + c;
                const int p = perm[jj];
                const float val =
                    (float)(*(const __fp16*)(lds + swzb(p >> 6, p & 63))) * diag_g[jj];
                B[ni][j] = (__fp16)val;
            }
#pragma unroll
        for (int ni = 0; ni < 4; ++ni)
#pragma unroll
            for (int mi = 0; mi < 4; ++mi)
                D[mi][ni] = MFMA16(AF(mi, kb), B[ni], D[mi][ni]);
    }
    __syncthreads();

    // j3: stage 0.125*T3 at layout (d-axis = d2, 2B-axis = a2)
#pragma unroll
    for (int mi = 0; mi < 4; ++mi)
#pragma unroll
        for (int ni = 0; ni < 4; ++ni) {
            union { unsigned long long u; pk2 p[2]; } w;
            w.p[0] = __builtin_amdgcn_cvt_pkrtz(D[mi][ni][0] * 0.125f, D[mi][ni][1] * 0.125f);
            w.p[1] = __builtin_amdgcn_cvt_pkrtz(D[mi][ni][2] * 0.125f, D[mi][ni][3] * 0.125f);
            *(unsigned long long*)(lds + swzb(ni * 16 + c, mi * 16 + g * 4)) = w.u;
        }
    __syncthreads();

    // ================= FWHT #2, step b: Y^T = H * T3^T =================
#pragma unroll
    for (int mi = 0; mi < 4; ++mi)
#pragma unroll
        for (int ni = 0; ni < 4; ++ni) D[mi][ni] = (f32x4){0.f, 0.f, 0.f, 0.f};
#pragma unroll
    for (int kb = 0; kb < 2; ++kb) {
        f16x8 B[4];
#pragma unroll
        for (int ni = 0; ni < 4; ++ni)
#pragma unroll
            for (int j = 0; j < 8; ++j)
                B[ni][j] = *(const __fp16*)(lds + swzb(kb * 32 + g * 8 + j, ni * 16 + c));
#pragma unroll
        for (int ni = 0; ni < 4; ++ni)
#pragma unroll
            for (int mi = 0; mi < 4; ++mi)
                D[mi][ni] = MFMA16(AF(mi, kb), B[ni], D[mi][ni]);
    }

    // store: out[64*a2 + e2] = Y^T[e2][a2] * diag_s * 0.125.
    // Frag regs are e2-consecutive -> one float4 per (mi,ni) per lane; every
    // touched 64B line is written entirely by a single instruction.
#pragma unroll
    for (int mi = 0; mi < 4; ++mi)
#pragma unroll
        for (int ni = 0; ni < 4; ++ni) {
            const int ob = (ni * 16 + c) * 64 + mi * 16 + g * 4;
            const float4 sv = *(const float4*)(diag_s + ob);
            float4 o4;
            o4.x = D[mi][ni][0] * (sv.x * 0.125f);
            o4.y = D[mi][ni][1] * (sv.y * 0.125f);
            o4.z = D[mi][ni][2] * (sv.z * 0.125f);
            o4.w = D[mi][ni][3] * (sv.w * 0.125f);
            *(float4*)(outr + ob) = o4;
        }
}

extern "C" void kernel_launch(void* const* d_in, const int* in_sizes, int n_in,
                              void* d_out, int out_size, void* d_ws, size_t ws_size,
                              hipStream_t stream) {
    const float* x      = (const float*)d_in[0];
    const float* diag_s = (const float*)d_in[1];
    const float* diag_g = (const float*)d_in[2];
    const float* diag_b = (const float*)d_in[3];
    const int*   perm   = (const int*)d_in[4];
    float* out = (float*)d_out;

    const int batch = in_sizes[0] / FF_N;   // 16384 rows
    fastfood_mfma_kernel<<<batch, 64, 0, stream>>>(x, diag_s, diag_g, diag_b, perm, out);
}

// Round 5
// 149.273 us; speedup vs baseline: 1.4040x; 1.1900x over previous
//
#include <hip/hip_runtime.h>

#define FF_N 4096
#define S64 0.015625f   // 1/64, one per FWHT (total 1/4096 = 1/sqrt(N)^2)

// Injective, bank-balancing LDS swizzle (dword units). Verified patterns:
//  stride-256 & stride-16 passes -> exactly 2 lanes/bank (free on 32 banks);
//  stride-1 b128 pass -> perfectly balanced (8 inherent passes, no excess);
//  max A(4095) = 4723 dwords = 18.9 KB -> 8 blocks/CU -> 32 waves/CU (100%).
__device__ __forceinline__ int A(int e) {
    return e + 4 * (e >> 5) + 8 * (e >> 8);
}

// In-register 16-point unnormalized WHT; static indexing only (stays in VGPRs).
__device__ __forceinline__ void h16(float v[16]) {
#pragma unroll
    for (int b = 1; b < 16; b <<= 1) {
#pragma unroll
        for (int r = 0; r < 16; ++r) {
            if ((r & b) == 0) {
                const float u = v[r];
                const float w = v[r | b];
                v[r]     = u + w;
                v[r | b] = u - w;
            }
        }
    }
}

// One row per 256-thread block; 16 f32/thread; H_4096 as three H16 digit passes
// per FWHT through swizzled f32 LDS. Code is small + looped (fits I-cache),
// the pipeline is exactly fp32 end-to-end.
__global__ __launch_bounds__(256) void fastfood_r16_kernel(
    const float* __restrict__ x,
    const float* __restrict__ diag_s,
    const float* __restrict__ diag_g,
    const float* __restrict__ diag_b,
    const int*   __restrict__ perm,
    float* __restrict__ out)
{
    __shared__ float lds[4724];
    const int t = threadIdx.x;
    const size_t row = blockIdx.x;
    const float* __restrict__ xr   = x   + row * (size_t)FF_N;
    float* __restrict__       outr = out + row * (size_t)FF_N;

    float v[16];

    // ---- load (float4, fully coalesced) * diag_b; H16 on bits 0-3; S=1 write ----
    {
        const float4* __restrict__ x4 = (const float4*)(xr + 16 * t);
        const float4* __restrict__ b4 = (const float4*)(diag_b + 16 * t);
#pragma unroll
        for (int q = 0; q < 4; ++q) {
            const float4 xv = x4[q];
            const float4 bv = b4[q];
            v[4 * q + 0] = xv.x * bv.x;
            v[4 * q + 1] = xv.y * bv.y;
            v[4 * q + 2] = xv.z * bv.z;
            v[4 * q + 3] = xv.w * bv.w;
        }
        h16(v);
#pragma unroll
        for (int q = 0; q < 4; ++q)
            *(float4*)&lds[A(16 * t + 4 * q)] =
                make_float4(v[4 * q], v[4 * q + 1], v[4 * q + 2], v[4 * q + 3]);
    }
    __syncthreads();

    // ---- FWHT1 pass over bits 4-7 (stride 16), in-place ----
    {
        const int base = ((t >> 4) << 8) + (t & 15);
#pragma unroll
        for (int j = 0; j < 16; ++j) v[j] = lds[A(base + (j << 4))];
        h16(v);
#pragma unroll
        for (int j = 0; j < 16; ++j) lds[A(base + (j << 4))] = v[j];
    }
    __syncthreads();

    // ---- FWHT1 pass over bits 8-11 (stride 256), in-place ----
    {
#pragma unroll
        for (int j = 0; j < 16; ++j) v[j] = lds[A(t + (j << 8))];
        h16(v);
#pragma unroll
        for (int j = 0; j < 16; ++j) lds[A(t + (j << 8))] = v[j];
    }
    __syncthreads();

    // ---- permutation gather * (diag_g/64); H16 on bits 0-3; S=1 write ----
    {
        const int4*   __restrict__ p4 = (const int4*)(perm + 16 * t);
        const float4* __restrict__ g4 = (const float4*)(diag_g + 16 * t);
        int   p[16];
        float g[16];
#pragma unroll
        for (int q = 0; q < 4; ++q) {
            const int4   pv = p4[q];
            const float4 gv = g4[q];
            p[4 * q + 0] = pv.x; p[4 * q + 1] = pv.y;
            p[4 * q + 2] = pv.z; p[4 * q + 3] = pv.w;
            g[4 * q + 0] = gv.x; g[4 * q + 1] = gv.y;
            g[4 * q + 2] = gv.z; g[4 * q + 3] = gv.w;
        }
#pragma unroll
        for (int j = 0; j < 16; ++j) v[j] = lds[A(p[j])] * (g[j] * S64);
        h16(v);
        __syncthreads();   // all gather reads done before overwrite
#pragma unroll
        for (int q = 0; q < 4; ++q)
            *(float4*)&lds[A(16 * t + 4 * q)] =
                make_float4(v[4 * q], v[4 * q + 1], v[4 * q + 2], v[4 * q + 3]);
    }
    __syncthreads();

    // ---- FWHT2 pass over bits 4-7 (stride 16), in-place ----
    {
        const int base = ((t >> 4) << 8) + (t & 15);
#pragma unroll
        for (int j = 0; j < 16; ++j) v[j] = lds[A(base + (j << 4))];
        h16(v);
#pragma unroll
        for (int j = 0; j < 16; ++j) lds[A(base + (j << 4))] = v[j];
    }
    __syncthreads();

    // ---- FWHT2 final pass (stride 256) + diag_s/64 -> global (coalesced) ----
    {
#pragma unroll
        for (int j = 0; j < 16; ++j) v[j] = lds[A(t + (j << 8))];
        h16(v);
#pragma unroll
        for (int j = 0; j < 16; ++j) {
            const int e = (j << 8) + t;
            outr[e] = v[j] * (diag_s[e] * S64);
        }
    }
}

extern "C" void kernel_launch(void* const* d_in, const int* in_sizes, int n_in,
                              void* d_out, int out_size, void* d_ws, size_t ws_size,
                              hipStream_t stream) {
    const float* x      = (const float*)d_in[0];
    const float* diag_s = (const float*)d_in[1];
    const float* diag_g = (const float*)d_in[2];
    const float* diag_b = (const float*)d_in[3];
    const int*   perm   = (const int*)d_in[4];
    float* out = (float*)d_out;

    const int batch = in_sizes[0] / FF_N;   // 16384 rows
    fastfood_r16_kernel<<<batch, 256, 0, stream>>>(x, diag_s, diag_g, diag_b, perm, out);
}

// Round 6
// 143.647 us; speedup vs baseline: 1.4590x; 1.0392x over previous
//
#include <hip/hip_runtime.h>

#define FF_N 4096
#define S64  0.015625f   // 1/64 per FWHT (total 1/4096)

// Global pad-128 layout (dword units): A(a) = a + 4*(a>>7).
// Verified conflict-free for: f4 writes at 16t+4q (8 lanes/quad, optimal),
// stride-16 reads (2/bank), stride-256 reads (2/bank). Affine per pass.
#define PAD(a) ((a) + 4 * ((a) >> 7))

// In-register 16-point unnormalized WHT (static indexing -> VGPRs only).
__device__ __forceinline__ void h16(float v[16]) {
#pragma unroll
    for (int b = 1; b < 16; b <<= 1) {
#pragma unroll
        for (int r = 0; r < 16; ++r) {
            if ((r & b) == 0) {
                const float u = v[r];
                const float w = v[r | b];
                v[r]     = u + w;
                v[r | b] = u - w;
            }
        }
    }
}

// One row per 256-thread block, 16 f32/thread, radix-16 digit-rotation:
// every LDS WRITE is ds_write_b128 (output digit placed contiguously),
// every LDS READ is scalar at an affine conflict-free pattern.
// Digits: e = 256*d2 + 16*d1 + d0.
//  W1[d2][d1][d0]  W2[d2][d0][d1]  W3[d0][d1][d2](gather layout)
//  W4[d2'][d1'][d0']  W5: 272*d2' + 16*d0' + d1' + 4*(d0'>>2)  (own spread)
__global__ __launch_bounds__(256) void fastfood_r16v_kernel(
    const float* __restrict__ x,
    const float* __restrict__ diag_s,
    const float* __restrict__ diag_g,
    const float* __restrict__ diag_b,
    const int*   __restrict__ perm,
    float* __restrict__ out)
{
    __shared__ __align__(16) float lds[4352];   // max(PAD(4095)=4219, W5 max 4347)
    const int t = threadIdx.x;
    const size_t row = blockIdx.x;
    const float* __restrict__ xr   = x   + row * (size_t)FF_N;
    float* __restrict__       outr = out + row * (size_t)FF_N;

    // Per-thread affine bases (computed once).
    const int T  = t >> 4;        // high nibble
    const int c  = t & 15;        // low nibble
    const int B1 = PAD(16 * t);                       // f4-write base (W1..W4)
    const int B2 = 256 * T + c + 8 * T;               // stride-16 read base (pad folded)
    const int B3 = t + 4 * (t >> 7);                  // stride-264 read base (W2)
    const int B5 = 272 * T + 16 * c + 4 * (c >> 2);   // W5 write base
    const int B6 = 16 * c + T + 4 * (c >> 2);         // W5 read base

    float v[16];

    // ---- P1: load x*diag_b (f4, coalesced); h16 over d0; W1 writes (f4) ----
    {
        const float4* __restrict__ x4 = (const float4*)(xr + 16 * t);
        const float4* __restrict__ b4 = (const float4*)(diag_b + 16 * t);
#pragma unroll
        for (int q = 0; q < 4; ++q) {
            const float4 xv = x4[q];
            const float4 bv = b4[q];
            v[4 * q + 0] = xv.x * bv.x;
            v[4 * q + 1] = xv.y * bv.y;
            v[4 * q + 2] = xv.z * bv.z;
            v[4 * q + 3] = xv.w * bv.w;
        }
        h16(v);
#pragma unroll
        for (int q = 0; q < 4; ++q)
            *(float4*)&lds[B1 + 4 * q] =
                make_float4(v[4 * q], v[4 * q + 1], v[4 * q + 2], v[4 * q + 3]);
    }
    __syncthreads();

    // ---- P2: read W1 (stride-16, affine); h16 over d1 ----
#pragma unroll
    for (int j = 0; j < 16; ++j) v[j] = lds[B2 + 16 * j + 4 * (j >> 3)];
    h16(v);
    __syncthreads();
    // W2 writes (f4): d1 contiguous
#pragma unroll
    for (int q = 0; q < 4; ++q)
        *(float4*)&lds[B1 + 4 * q] =
            make_float4(v[4 * q], v[4 * q + 1], v[4 * q + 2], v[4 * q + 3]);
    __syncthreads();

    // ---- P3: read W2 (stride-264, affine); h16 over d2 (FWHT1 done) ----
#pragma unroll
    for (int j = 0; j < 16; ++j) v[j] = lds[B3 + 264 * j];
    h16(v);
    __syncthreads();
    // W3 writes (f4): d2 contiguous -> gather layout [d0][d1][d2]
#pragma unroll
    for (int q = 0; q < 4; ++q)
        *(float4*)&lds[B1 + 4 * q] =
            make_float4(v[4 * q], v[4 * q + 1], v[4 * q + 2], v[4 * q + 3]);
    __syncthreads();

    // ---- P4: permutation gather * (diag_g/64); h16 over d0' ----
    {
        const int4*   __restrict__ p4 = (const int4*)(perm + 16 * t);
        const float4* __restrict__ g4 = (const float4*)(diag_g + 16 * t);
        int   p[16];
        float g[16];
#pragma unroll
        for (int q = 0; q < 4; ++q) {
            const int4   pv = p4[q];
            const float4 gv = g4[q];
            p[4 * q + 0] = pv.x; p[4 * q + 1] = pv.y;
            p[4 * q + 2] = pv.z; p[4 * q + 3] = pv.w;
            g[4 * q + 0] = gv.x; g[4 * q + 1] = gv.y;
            g[4 * q + 2] = gv.z; g[4 * q + 3] = gv.w;
        }
#pragma unroll
        for (int j = 0; j < 16; ++j) {
            const int pe = p[j];
            const int a  = ((pe & 15) << 8) + (pe & 240) + (pe >> 8);  // W3 addr
            v[j] = lds[PAD(a)] * (g[j] * S64);
        }
        h16(v);
    }
    __syncthreads();
    // W4 writes (f4): d0' contiguous
#pragma unroll
    for (int q = 0; q < 4; ++q)
        *(float4*)&lds[B1 + 4 * q] =
            make_float4(v[4 * q], v[4 * q + 1], v[4 * q + 2], v[4 * q + 3]);
    __syncthreads();

    // ---- P5: read W4 (stride-16, affine); h16 over d1' ----
#pragma unroll
    for (int j = 0; j < 16; ++j) v[j] = lds[B2 + 16 * j + 4 * (j >> 3)];
    h16(v);
    __syncthreads();
    // W5 writes (f4): d1' contiguous, custom spread layout
#pragma unroll
    for (int q = 0; q < 4; ++q)
        *(float4*)&lds[B5 + 4 * q] =
            make_float4(v[4 * q], v[4 * q + 1], v[4 * q + 2], v[4 * q + 3]);
    __syncthreads();

    // ---- P6: read W5 (stride-272, affine); h16 over d2'; store *diag_s/64 ----
#pragma unroll
    for (int j = 0; j < 16; ++j) v[j] = lds[B6 + 272 * j];
    h16(v);
#pragma unroll
    for (int j = 0; j < 16; ++j) {
        const int e = (j << 8) + t;      // = 256*d2' + 16*d1' + d0', coalesced
        outr[e] = v[j] * (diag_s[e] * S64);
    }
}

extern "C" void kernel_launch(void* const* d_in, const int* in_sizes, int n_in,
                              void* d_out, int out_size, void* d_ws, size_t ws_size,
                              hipStream_t stream) {
    const float* x      = (const float*)d_in[0];
    const float* diag_s = (const float*)d_in[1];
    const float* diag_g = (const float*)d_in[2];
    const float* diag_b = (const float*)d_in[3];
    const int*   perm   = (const int*)d_in[4];
    float* out = (float*)d_out;

    const int batch = in_sizes[0] / FF_N;   // 16384 rows
    fastfood_r16v_kernel<<<batch, 256, 0, stream>>>(x, diag_s, diag_g, diag_b, perm, out);
}